// Round 1
// baseline (404.676 us; speedup 1.0000x reference)
//
#include <hip/hip_runtime.h>

constexpr int NROWS  = 131072;
constexpr int LDIM   = 300;
constexpr int KDIM   = 600;
constexpr int NPAD   = 320;              // 10 n-tiles of 32
constexpr int KGRP   = 76;               // 608 / 8
constexpr int MTILE  = 128;
constexpr int NBLKS  = NROWS / MTILE;    // 1024
constexpr int KSTEPS = 19;               // 608 / 32
constexpr int WT_ELEMS = KGRP * NPAD * 8;        // 194560 bf16
constexpr size_t PART_OFF = 393216;              // byte offset of partials in ws

typedef __bf16 bf16x8 __attribute__((ext_vector_type(8)));
typedef float  f32x16 __attribute__((ext_vector_type(16)));
typedef const unsigned int __attribute__((address_space(1))) gu32;
typedef unsigned int __attribute__((address_space(3))) lu32;

__device__ __forceinline__ unsigned short f2bf(float f) {
    unsigned u = __float_as_uint(f);
    u += 0x7fffu + ((u >> 16) & 1u);      // RNE; inputs are finite
    return (unsigned short)(u >> 16);
}

// ---------------- kernel 1: W1 -> bf16, fragment-ready layout [kg][n][j] ----
__global__ void prep_w1(const float* __restrict__ w1, unsigned short* __restrict__ wt) {
    int idx = blockIdx.x * 256 + threadIdx.x;
    if (idx >= WT_ELEMS) return;
    int j    = idx & 7;
    int rest = idx >> 3;
    int n    = rest % NPAD;
    int kg   = rest / NPAD;
    int k    = kg * 8 + j;
    float v = 0.f;
    if (k < KDIM && n < LDIM) v = w1[k * LDIM + n];
    wt[idx] = f2bf(v);
}

// ---------------- kernel 2: fused GEMM + epilogue ---------------------------
__launch_bounds__(256, 2)
__global__ void main_kernel(const float* __restrict__ sbj, const float* __restrict__ obj,
                            const float* __restrict__ rlts,
                            const float* __restrict__ spa_w, const float* __restrict__ spa_b,
                            const float* __restrict__ b1, const float* __restrict__ w2,
                            const float* __restrict__ b2,
                            const unsigned short* __restrict__ wt,
                            float* __restrict__ out_scores, float* __restrict__ part) {
    __shared__ __attribute__((aligned(16))) short A_lds[4 * 128 * 8];   // 8 KB
    __shared__ __attribute__((aligned(16))) short B_lds[4 * 320 * 8];   // 20 KB
    __shared__ float lanpart[2][128];
    __shared__ float redbuf[4][8];

    const int tid  = threadIdx.x;
    const int lane = tid & 63;
    const int wv   = tid >> 6;     // 0..3
    const int wm   = wv >> 1;      // wave row group
    const int wn   = wv & 1;       // wave col group
    const int l31  = lane & 31;
    const int l5   = lane >> 5;

    const int  blk  = blockIdx.x;
    const long row0 = (long)blk * MTILE;

    const int a_quad = tid & 7;    // k-group of 4 within 32
    const int a_rowb = tid >> 3;   // 0..31

    f32x16 acc[2][5];
    #pragma unroll
    for (int mt = 0; mt < 2; ++mt)
        #pragma unroll
        for (int nt = 0; nt < 5; ++nt)
            acc[mt][nt] = (f32x16)(0.f);

    for (int kt = 0; kt < KSTEPS; ++kt) {
        // ---- stage B: contiguous async copy global->LDS (20480 B) ----
        {
            const unsigned short* src = wt + (size_t)kt * (4 * 320 * 8) + wv * 2560 + lane * 8;
            short* dst = &B_lds[wv * 2560 + lane * 8];
            #pragma unroll
            for (int it = 0; it < 5; ++it) {
                __builtin_amdgcn_global_load_lds((gu32*)(src + it * 512),
                                                 (lu32*)(dst + it * 512), 16, 0, 0);
            }
        }
        // ---- stage A: coalesced float4, relu, cvt bf16 ----
        {
            const int kglob0 = kt * 32 + a_quad * 4;   // multiple of 4; never straddles 300
            #pragma unroll
            for (int i = 0; i < 4; ++i) {
                const int  row  = a_rowb + i * 32;
                const long grow = row0 + row;
                float4 v;
                if (kglob0 < LDIM) {
                    v = *(const float4*)(sbj + grow * LDIM + kglob0);
                } else if (kglob0 < KDIM) {
                    v = *(const float4*)(obj + grow * LDIM + (kglob0 - LDIM));
                } else {
                    v = make_float4(0.f, 0.f, 0.f, 0.f);
                }
                unsigned h0 = f2bf(fmaxf(v.x, 0.f));
                unsigned h1 = f2bf(fmaxf(v.y, 0.f));
                unsigned h2 = f2bf(fmaxf(v.z, 0.f));
                unsigned h3 = f2bf(fmaxf(v.w, 0.f));
                uint2 pk = make_uint2(h0 | (h1 << 16), h2 | (h3 << 16));
                *(uint2*)&A_lds[((a_quad >> 1) * 128 + row) * 8 + (a_quad & 1) * 4] = pk;
            }
        }
        __syncthreads();
        // ---- MFMA: 2 inner k-steps of 16 ----
        #pragma unroll
        for (int ki = 0; ki < 2; ++ki) {
            const int half = ki * 2 + l5;
            bf16x8 af[2];
            #pragma unroll
            for (int mt = 0; mt < 2; ++mt) {
                const int row = wm * 64 + mt * 32 + l31;
                af[mt] = *(const bf16x8*)&A_lds[(half * 128 + row) * 8];
            }
            #pragma unroll
            for (int nt = 0; nt < 5; ++nt) {
                const int n = wn * 160 + nt * 32 + l31;
                bf16x8 bfr = *(const bf16x8*)&B_lds[(half * 320 + n) * 8];
                #pragma unroll
                for (int mt = 0; mt < 2; ++mt)
                    acc[mt][nt] = __builtin_amdgcn_mfma_f32_32x32x16_bf16(af[mt], bfr, acc[mt][nt], 0, 0, 0);
            }
        }
        __syncthreads();
    }

    // ---- epilogue: bias + relu + dot with w2, per-lane partial over cols ----
    float part_r[2][16];
    #pragma unroll
    for (int mt = 0; mt < 2; ++mt)
        #pragma unroll
        for (int r = 0; r < 16; ++r) part_r[mt][r] = 0.f;

    #pragma unroll
    for (int nt = 0; nt < 5; ++nt) {
        const int n = wn * 160 + nt * 32 + l31;
        if (n < LDIM) {
            const float b1n = b1[n];
            const float w2n = w2[n];
            #pragma unroll
            for (int mt = 0; mt < 2; ++mt)
                #pragma unroll
                for (int r = 0; r < 16; ++r) {
                    float h = fmaxf(acc[mt][nt][r] + b1n, 0.f);
                    part_r[mt][r] = fmaf(h, w2n, part_r[mt][r]);
                }
        }
    }
    // butterfly across the 32 lanes holding different cols
    #pragma unroll
    for (int off = 1; off < 32; off <<= 1)
        #pragma unroll
        for (int mt = 0; mt < 2; ++mt)
            #pragma unroll
            for (int r = 0; r < 16; ++r)
                part_r[mt][r] += __shfl_xor(part_r[mt][r], off, 64);

    if (l31 == 0) {
        #pragma unroll
        for (int mt = 0; mt < 2; ++mt)
            #pragma unroll
            for (int r = 0; r < 16; ++r) {
                // C/D layout (m74/m101): row = (reg&3) + 8*(reg>>2) + 4*(lane>>5)
                const int rl = wm * 64 + mt * 32 + (r & 3) + 8 * (r >> 2) + 4 * l5;
                lanpart[wn][rl] = part_r[mt][r];
            }
    }
    __syncthreads();

    // ---- per-row: box features, sigmoid, loss terms ----
    float s_loss = 0.f, s_cp = 0.f, s_cn = 0.f, s_pr = 0.f, s_nr = 0.f;
    if (tid < 128) {
        const long g   = row0 + tid;
        const float lan = lanpart[0][tid] + lanpart[1][tid] + b2[0];
        const float* rr = rlts + g * 15;
        const float label = rr[4];
        const float sx1 = rr[5],  sy1 = rr[6],  sx2 = rr[7],  sy2 = rr[8];
        const float ox1 = rr[10], oy1 = rr[11], ox2 = rr[12], oy2 = rr[13];
        const float sw = sx2 - sx1, sh = sy2 - sy1, ow = ox2 - ox1, oh = oy2 - oy1;
        float bs = spa_w[0] * ((sx1 - ox1) / sw)
                 + spa_w[1] * ((sy1 - oy1) / sh)
                 + spa_w[2] * logf(sw / ow)
                 + spa_w[3] * logf(sh / oh)
                 + spa_w[4] * ((ox1 - sx1) / ow)
                 + spa_w[5] * ((oy1 - sy1) / oh)
                 + spa_w[6] * logf(ow / sw)
                 + spa_w[7] * logf(oh / sh)
                 + spa_b[0];
        const float z = lan + bs;
        const float s = 1.f / (1.f + expf(-z));
        out_scores[g] = s;
        const float ls = fmaxf(logf(fminf(fmaxf(s, 1e-12f), 1.f)), -100.f);
        const float l1 = fmaxf(logf(fminf(fmaxf(1.f - s, 1e-12f), 1.f)), -100.f);
        const bool ys = label > 0.f;
        s_loss = ys ? ls : l1;
        s_cp   = ys ? 1.f : 0.f;
        s_cn   = ys ? 0.f : 1.f;
        s_pr   = (!ys && s >= 0.5f) ? 1.f : 0.f;  // "N_pos_right" per reference
        s_nr   = (ys && s < 0.5f)  ? 1.f : 0.f;   // "N_neg_right" per reference
    }
    #pragma unroll
    for (int off = 1; off < 64; off <<= 1) {
        s_loss += __shfl_xor(s_loss, off, 64);
        s_cp   += __shfl_xor(s_cp, off, 64);
        s_cn   += __shfl_xor(s_cn, off, 64);
        s_pr   += __shfl_xor(s_pr, off, 64);
        s_nr   += __shfl_xor(s_nr, off, 64);
    }
    if (lane == 0) {
        redbuf[wv][0] = s_loss; redbuf[wv][1] = s_cp; redbuf[wv][2] = s_cn;
        redbuf[wv][3] = s_pr;   redbuf[wv][4] = s_nr;
    }
    __syncthreads();
    if (tid == 0) {
        float t0 = 0.f, t1 = 0.f, t2 = 0.f, t3 = 0.f, t4 = 0.f;
        for (int w = 0; w < 4; ++w) {
            t0 += redbuf[w][0]; t1 += redbuf[w][1]; t2 += redbuf[w][2];
            t3 += redbuf[w][3]; t4 += redbuf[w][4];
        }
        part[blk * 8 + 0] = t0; part[blk * 8 + 1] = t1; part[blk * 8 + 2] = t2;
        part[blk * 8 + 3] = t3; part[blk * 8 + 4] = t4;
    }
}

// ---------------- kernel 3: fold 1024 block partials ------------------------
__global__ void final_reduce(const float* __restrict__ part, float* __restrict__ out) {
    __shared__ float red[4][8];
    const int tid = threadIdx.x;
    const int lane = tid & 63, wv = tid >> 6;
    float a0 = 0.f, a1 = 0.f, a2 = 0.f, a3 = 0.f, a4 = 0.f;
    for (int b = tid; b < NBLKS; b += 256) {
        a0 += part[b * 8 + 0]; a1 += part[b * 8 + 1]; a2 += part[b * 8 + 2];
        a3 += part[b * 8 + 3]; a4 += part[b * 8 + 4];
    }
    #pragma unroll
    for (int off = 1; off < 64; off <<= 1) {
        a0 += __shfl_xor(a0, off, 64); a1 += __shfl_xor(a1, off, 64);
        a2 += __shfl_xor(a2, off, 64); a3 += __shfl_xor(a3, off, 64);
        a4 += __shfl_xor(a4, off, 64);
    }
    if (lane == 0) { red[wv][0] = a0; red[wv][1] = a1; red[wv][2] = a2; red[wv][3] = a3; red[wv][4] = a4; }
    __syncthreads();
    if (tid == 0) {
        float t0 = 0.f, t1 = 0.f, t2 = 0.f, t3 = 0.f, t4 = 0.f;
        for (int w = 0; w < 4; ++w) {
            t0 += red[w][0]; t1 += red[w][1]; t2 += red[w][2]; t3 += red[w][3]; t4 += red[w][4];
        }
        out[NROWS + 0] = -t0 / (float)NROWS;       // loss
        out[NROWS + 1] = t3 / t1;                  // recall_pos = N_pos_right / N_pos
        out[NROWS + 2] = t4 / t2;                  // recall_neg = N_neg_right / N_neg
        out[NROWS + 3] = (t3 + t4) / (t1 + t2);    // recall_all
    }
}

extern "C" void kernel_launch(void* const* d_in, const int* in_sizes, int n_in,
                              void* d_out, int out_size, void* d_ws, size_t ws_size,
                              hipStream_t stream) {
    const float* sbj   = (const float*)d_in[0];
    const float* obj   = (const float*)d_in[1];
    const float* rlts  = (const float*)d_in[2];
    const float* spa_w = (const float*)d_in[3];
    const float* spa_b = (const float*)d_in[4];
    const float* w1    = (const float*)d_in[5];
    const float* b1    = (const float*)d_in[6];
    const float* w2    = (const float*)d_in[7];
    const float* b2    = (const float*)d_in[8];
    float* out = (float*)d_out;

    unsigned short* wt = (unsigned short*)d_ws;
    float* part = (float*)((char*)d_ws + PART_OFF);

    prep_w1<<<(WT_ELEMS + 255) / 256, 256, 0, stream>>>(w1, wt);
    main_kernel<<<NBLKS, 256, 0, stream>>>(sbj, obj, rlts, spa_w, spa_b, b1, w2, b2, wt, out, part);
    final_reduce<<<1, 256, 0, stream>>>(part, out);
}

// Round 2
// 383.953 us; speedup vs baseline: 1.0540x; 1.0540x over previous
//
#include <hip/hip_runtime.h>

constexpr int NROWS  = 131072;
constexpr int LDIM   = 300;
constexpr int KDIM   = 600;
constexpr int NPAD   = 320;
constexpr int KGRP   = 76;               // 608 / 8
constexpr int MTILE  = 64;
constexpr int NBLKS  = NROWS / MTILE;    // 2048
constexpr int KSTEPS = 19;               // 608 / 32
constexpr int WT_ELEMS = KGRP * NPAD * 8;        // 194560 bf16
constexpr size_t PART_OFF = 393216;              // byte offset of partials in ws
constexpr int ASTRIDE = 40;              // shorts per row (80 B) — conflict-free

typedef __bf16 bf16x8 __attribute__((ext_vector_type(8)));
typedef float  f32x4  __attribute__((ext_vector_type(4)));

__device__ __forceinline__ unsigned short f2bf(float f) {
    unsigned u = __float_as_uint(f);
    u += 0x7fffu + ((u >> 16) & 1u);      // RNE; inputs are finite
    return (unsigned short)(u >> 16);
}

// ---------------- kernel 1: W1 -> bf16, fragment-ready layout [kg][n][j] ----
__global__ void prep_w1(const float* __restrict__ w1, unsigned short* __restrict__ wt) {
    int idx = blockIdx.x * 256 + threadIdx.x;
    if (idx >= WT_ELEMS) return;
    int j    = idx & 7;
    int rest = idx >> 3;
    int n    = rest % NPAD;
    int kg   = rest / NPAD;
    int k    = kg * 8 + j;
    float v = 0.f;
    if (k < KDIM && n < LDIM) v = w1[k * LDIM + n];
    wt[idx] = f2bf(v);
}

// ---------------- kernel 2: fused GEMM + epilogue ---------------------------
__launch_bounds__(256, 3)
__global__ void main_kernel(const float* __restrict__ sbj, const float* __restrict__ obj,
                            const float* __restrict__ rlts,
                            const float* __restrict__ spa_w, const float* __restrict__ spa_b,
                            const float* __restrict__ b1, const float* __restrict__ w2,
                            const float* __restrict__ b2,
                            const unsigned short* __restrict__ wt,
                            float* __restrict__ out_scores, float* __restrict__ part) {
    __shared__ __attribute__((aligned(16))) short A_lds[2][MTILE * ASTRIDE]; // 10240 B
    __shared__ float lanpart[4][MTILE];
    __shared__ float redbuf[4][8];

    const int tid  = threadIdx.x;
    const int lane = tid & 63;
    const int wv   = tid >> 6;     // 0..3 — each wave owns 80 cols
    const int l4   = lane & 15;    // MFMA row/col index
    const int q4   = lane >> 4;    // MFMA k-group (0..3)
    const int nbase = wv * 80;

    const int  blk  = blockIdx.x;
    const long row0 = (long)blk * MTILE;

    // A staging map: thread t loads rows (t>>3) and (t>>3)+32, k-quad t&7
    const int a_quad = tid & 7;
    const int a_row  = tid >> 3;   // 0..31

    f32x4 acc[4][5];
    #pragma unroll
    for (int rt = 0; rt < 4; ++rt)
        #pragma unroll
        for (int ct = 0; ct < 5; ++ct)
            acc[rt][ct] = (f32x4)(0.f);

    float4 pre[2];

    auto load_A = [&](int kt) {
        const int k0 = kt * 32 + a_quad * 4;   // mult of 4; 300 % 4 == 0 → no straddle
        #pragma unroll
        for (int i = 0; i < 2; ++i) {
            const long grow = row0 + a_row + i * 32;
            if (k0 < LDIM)       pre[i] = *(const float4*)(sbj + grow * LDIM + k0);
            else if (k0 < KDIM)  pre[i] = *(const float4*)(obj + grow * LDIM + (k0 - LDIM));
            else                 pre[i] = make_float4(0.f, 0.f, 0.f, 0.f);
        }
    };
    auto store_A = [&](int buf) {
        #pragma unroll
        for (int i = 0; i < 2; ++i) {
            const int row = a_row + i * 32;
            unsigned h0 = f2bf(fmaxf(pre[i].x, 0.f));
            unsigned h1 = f2bf(fmaxf(pre[i].y, 0.f));
            unsigned h2 = f2bf(fmaxf(pre[i].z, 0.f));
            unsigned h3 = f2bf(fmaxf(pre[i].w, 0.f));
            uint2 pk = make_uint2(h0 | (h1 << 16), h2 | (h3 << 16));
            *(uint2*)&A_lds[buf][row * ASTRIDE + a_quad * 4] = pk;
        }
    };

    load_A(0);
    store_A(0);

    for (int kt = 0; kt < KSTEPS; ++kt) {
        const int buf = kt & 1;
        __syncthreads();                       // A_lds[buf] ready; no vmem outstanding here
        if (kt + 1 < KSTEPS) load_A(kt + 1);   // issue global loads; latency hides behind MFMA

        // A fragments from LDS (conflict-free stride-40 layout)
        bf16x8 af[4];
        #pragma unroll
        for (int rt = 0; rt < 4; ++rt)
            af[rt] = *(const bf16x8*)&A_lds[buf][(rt * 16 + l4) * ASTRIDE + q4 * 8];

        // B fragments straight from global (L2-resident, coalesced 16B/lane)
        bf16x8 bfr[5];
        #pragma unroll
        for (int ct = 0; ct < 5; ++ct) {
            const int kg = kt * 4 + q4;
            bfr[ct] = *(const bf16x8*)(wt + ((size_t)kg * NPAD + nbase + ct * 16 + l4) * 8);
        }
        #pragma unroll
        for (int ct = 0; ct < 5; ++ct)
            #pragma unroll
            for (int rt = 0; rt < 4; ++rt)
                acc[rt][ct] = __builtin_amdgcn_mfma_f32_16x16x32_bf16(af[rt], bfr[ct], acc[rt][ct], 0, 0, 0);

        if (kt + 1 < KSTEPS) store_A(buf ^ 1); // consume prefetch BEFORE next barrier
    }

    // ---- epilogue: bias + relu + dot with w2 ----
    // C/D layout (m89): col = lane&15, row = (lane>>4)*4 + reg
    float part_r[4][4];
    #pragma unroll
    for (int rt = 0; rt < 4; ++rt)
        #pragma unroll
        for (int r = 0; r < 4; ++r) part_r[rt][r] = 0.f;

    #pragma unroll
    for (int ct = 0; ct < 5; ++ct) {
        const int n = nbase + ct * 16 + l4;
        if (n < LDIM) {
            const float b1n = b1[n];
            const float w2n = w2[n];
            #pragma unroll
            for (int rt = 0; rt < 4; ++rt)
                #pragma unroll
                for (int r = 0; r < 4; ++r) {
                    float h = fmaxf(acc[rt][ct][r] + b1n, 0.f);
                    part_r[rt][r] = fmaf(h, w2n, part_r[rt][r]);
                }
        }
    }
    // reduce over the 16 col-lanes (xor of lane bits 0..3)
    #pragma unroll
    for (int off = 1; off < 16; off <<= 1)
        #pragma unroll
        for (int rt = 0; rt < 4; ++rt)
            #pragma unroll
            for (int r = 0; r < 4; ++r)
                part_r[rt][r] += __shfl_xor(part_r[rt][r], off, 64);

    if (l4 == 0) {
        #pragma unroll
        for (int rt = 0; rt < 4; ++rt)
            #pragma unroll
            for (int r = 0; r < 4; ++r)
                lanpart[wv][rt * 16 + q4 * 4 + r] = part_r[rt][r];
    }
    __syncthreads();

    // ---- per-row: box features, sigmoid, loss terms ----
    float s_loss = 0.f, s_cp = 0.f, s_cn = 0.f, s_pr = 0.f, s_nr = 0.f;
    if (tid < MTILE) {
        const long g   = row0 + tid;
        const float lan = lanpart[0][tid] + lanpart[1][tid] + lanpart[2][tid] + lanpart[3][tid] + b2[0];
        const float* rr = rlts + g * 15;
        const float label = rr[4];
        const float sx1 = rr[5],  sy1 = rr[6],  sx2 = rr[7],  sy2 = rr[8];
        const float ox1 = rr[10], oy1 = rr[11], ox2 = rr[12], oy2 = rr[13];
        const float sw = sx2 - sx1, sh = sy2 - sy1, ow = ox2 - ox1, oh = oy2 - oy1;
        float bs = spa_w[0] * ((sx1 - ox1) / sw)
                 + spa_w[1] * ((sy1 - oy1) / sh)
                 + spa_w[2] * logf(sw / ow)
                 + spa_w[3] * logf(sh / oh)
                 + spa_w[4] * ((ox1 - sx1) / ow)
                 + spa_w[5] * ((oy1 - sy1) / oh)
                 + spa_w[6] * logf(ow / sw)
                 + spa_w[7] * logf(oh / sh)
                 + spa_b[0];
        const float z = lan + bs;
        const float s = 1.f / (1.f + expf(-z));
        out_scores[g] = s;
        const float ls = fmaxf(logf(fminf(fmaxf(s, 1e-12f), 1.f)), -100.f);
        const float l1 = fmaxf(logf(fminf(fmaxf(1.f - s, 1e-12f), 1.f)), -100.f);
        const bool ys = label > 0.f;
        s_loss = ys ? ls : l1;
        s_cp   = ys ? 1.f : 0.f;
        s_cn   = ys ? 0.f : 1.f;
        s_pr   = (!ys && s >= 0.5f) ? 1.f : 0.f;  // "N_pos_right" per reference
        s_nr   = (ys && s < 0.5f)  ? 1.f : 0.f;   // "N_neg_right" per reference
    }
    #pragma unroll
    for (int off = 1; off < 64; off <<= 1) {
        s_loss += __shfl_xor(s_loss, off, 64);
        s_cp   += __shfl_xor(s_cp, off, 64);
        s_cn   += __shfl_xor(s_cn, off, 64);
        s_pr   += __shfl_xor(s_pr, off, 64);
        s_nr   += __shfl_xor(s_nr, off, 64);
    }
    if (lane == 0) {
        redbuf[wv][0] = s_loss; redbuf[wv][1] = s_cp; redbuf[wv][2] = s_cn;
        redbuf[wv][3] = s_pr;   redbuf[wv][4] = s_nr;
    }
    __syncthreads();
    if (tid == 0) {
        float t0 = 0.f, t1 = 0.f, t2 = 0.f, t3 = 0.f, t4 = 0.f;
        for (int w = 0; w < 4; ++w) {
            t0 += redbuf[w][0]; t1 += redbuf[w][1]; t2 += redbuf[w][2];
            t3 += redbuf[w][3]; t4 += redbuf[w][4];
        }
        part[blk * 8 + 0] = t0; part[blk * 8 + 1] = t1; part[blk * 8 + 2] = t2;
        part[blk * 8 + 3] = t3; part[blk * 8 + 4] = t4;
    }
}

// ---------------- kernel 3: fold 2048 block partials ------------------------
__global__ void final_reduce(const float* __restrict__ part, float* __restrict__ out) {
    __shared__ float red[4][8];
    const int tid = threadIdx.x;
    const int lane = tid & 63, wv = tid >> 6;
    float a0 = 0.f, a1 = 0.f, a2 = 0.f, a3 = 0.f, a4 = 0.f;
    for (int b = tid; b < NBLKS; b += 256) {
        a0 += part[b * 8 + 0]; a1 += part[b * 8 + 1]; a2 += part[b * 8 + 2];
        a3 += part[b * 8 + 3]; a4 += part[b * 8 + 4];
    }
    #pragma unroll
    for (int off = 1; off < 64; off <<= 1) {
        a0 += __shfl_xor(a0, off, 64); a1 += __shfl_xor(a1, off, 64);
        a2 += __shfl_xor(a2, off, 64); a3 += __shfl_xor(a3, off, 64);
        a4 += __shfl_xor(a4, off, 64);
    }
    if (lane == 0) { red[wv][0] = a0; red[wv][1] = a1; red[wv][2] = a2; red[wv][3] = a3; red[wv][4] = a4; }
    __syncthreads();
    if (tid == 0) {
        float t0 = 0.f, t1 = 0.f, t2 = 0.f, t3 = 0.f, t4 = 0.f;
        for (int w = 0; w < 4; ++w) {
            t0 += red[w][0]; t1 += red[w][1]; t2 += red[w][2]; t3 += red[w][3]; t4 += red[w][4];
        }
        out[NROWS + 0] = -t0 / (float)NROWS;       // loss
        out[NROWS + 1] = t3 / t1;                  // recall_pos
        out[NROWS + 2] = t4 / t2;                  // recall_neg
        out[NROWS + 3] = (t3 + t4) / (t1 + t2);    // recall_all
    }
}

extern "C" void kernel_launch(void* const* d_in, const int* in_sizes, int n_in,
                              void* d_out, int out_size, void* d_ws, size_t ws_size,
                              hipStream_t stream) {
    const float* sbj   = (const float*)d_in[0];
    const float* obj   = (const float*)d_in[1];
    const float* rlts  = (const float*)d_in[2];
    const float* spa_w = (const float*)d_in[3];
    const float* spa_b = (const float*)d_in[4];
    const float* w1    = (const float*)d_in[5];
    const float* b1    = (const float*)d_in[6];
    const float* w2    = (const float*)d_in[7];
    const float* b2    = (const float*)d_in[8];
    float* out = (float*)d_out;

    unsigned short* wt = (unsigned short*)d_ws;
    float* part = (float*)((char*)d_ws + PART_OFF);

    prep_w1<<<(WT_ELEMS + 255) / 256, 256, 0, stream>>>(w1, wt);
    main_kernel<<<NBLKS, 256, 0, stream>>>(sbj, obj, rlts, spa_w, spa_b, b1, w2, b2, wt, out, part);
    final_reduce<<<1, 256, 0, stream>>>(part, out);
}